// Round 6
// baseline (31.192 us; speedup 1.0000x reference)
//
#include <hip/hip_runtime.h>
#include <hip/hip_bf16.h>
#include <math.h>

#define B_ 128
#define S_ 512
#define E_ 64

typedef short bf16x8 __attribute__((ext_vector_type(8)));
typedef float f32x4 __attribute__((ext_vector_type(4)));

__device__ __forceinline__ unsigned short f2b(float f) {
  __hip_bfloat16 h = __float2bfloat16(f);
  unsigned short u;
  __builtin_memcpy(&u, &h, 2);
  return u;
}

// k1: pure-streaming normalize + bf16 compress. One wave = 16 rows; lane (c,g)
// owns row base+c, cols [16g,16g+16). Rows < B*S are U (scale 1); rows >= B*S
// are V (scale w0*cw). No LDS, no barriers -> should run at HBM BW.
__global__ __launch_bounds__(256) void prep_kernel(
    const float* __restrict__ ue, const float* __restrict__ ve,
    const float* __restrict__ cw, const float* __restrict__ pw,
    unsigned short* __restrict__ ubf, unsigned short* __restrict__ vbf) {
  const int tid = threadIdx.x;
  const int wv = tid >> 6, lane = tid & 63;
  const int c = lane & 15, g = lane >> 4;
  const int row = blockIdx.x * 64 + wv * 16 + c;  // 0 .. 2*B*S-1
  const int R = B_ * S_;
  const bool isV = row >= R;
  const int r0 = isV ? row - R : row;

  const float* src = (isV ? ve : ue) + (size_t)r0 * E_ + g * 16;
  f32x4 x0 = ((const f32x4*)src)[0];
  f32x4 x1 = ((const f32x4*)src)[1];
  f32x4 x2 = ((const f32x4*)src)[2];
  f32x4 x3 = ((const f32x4*)src)[3];

  float ss = 0.f;
#pragma unroll
  for (int j = 0; j < 4; ++j)
    ss = fmaf(x0[j], x0[j],
         fmaf(x1[j], x1[j], fmaf(x2[j], x2[j], fmaf(x3[j], x3[j], ss))));
  ss += __shfl_xor(ss, 16);
  ss += __shfl_xor(ss, 32);
  float s = 1.0f / fmaxf(sqrtf(ss), 1e-7f);
  if (isV) s *= pw[0] * cw[r0];

  bf16x8 o0, o1;
#pragma unroll
  for (int j = 0; j < 4; ++j) {
    o0[j] = (short)f2b(x0[j] * s); o0[4 + j] = (short)f2b(x1[j] * s);
    o1[j] = (short)f2b(x2[j] * s); o1[4 + j] = (short)f2b(x3[j] * s);
  }
  unsigned short* dst = (isV ? vbf : ubf) + (size_t)r0 * E_ + g * 16;
  *(bf16x8*)dst = o0;
  *(bf16x8*)(dst + 8) = o1;
}

// k2: LDS-free MFMA max-scan over cache-hot bf16. 512 blocks x 512 thr
// (2 blocks/CU). Block = (batch b, s-quarter sq) -> 128 s-rows, all 512 n.
// Wave (ws,wn) = 64 s x 128 n. A/B fragments load straight from global
// (V panel = 64 KB bf16, L2-resident; sibling blocks swizzled to one XCD).
// Mask folded into the MFMA C-operand as a -1e30 penalty.
__global__ __launch_bounds__(512, 2) void main_kernel(
    const unsigned short* __restrict__ ubf,
    const unsigned short* __restrict__ vbf,
    const float* __restrict__ mask, const float* __restrict__ pb,
    float* __restrict__ out) {
  __shared__ float comb[4][128];

  // bijective swizzle: all 4 sq-blocks of a batch on the same XCD (bx % 8)
  const int bx = blockIdx.x;
  const int b = (bx & 7) * 16 + (bx >> 5);
  const int sq = (bx >> 3) & 3;

  const int tid = threadIdx.x;
  const int wv = tid >> 6, lane = tid & 63;
  const int c = lane & 15, g = lane >> 4;
  const int ws = wv >> 2;  // 0..1 : 64 s-rows
  const int wn = wv & 3;   // 0..3 : 128 n

  const unsigned short* __restrict__ Ub = ubf + ((size_t)b * S_ + sq * 128) * E_;
  const unsigned short* __restrict__ Vb = vbf + (size_t)b * S_ * E_;
  const float* __restrict__ mb = mask + (size_t)b * S_;

  // A fragments: rows ws*64 + st*16 + c; k chunks [8g,8g+8) and [32+8g,+8)
  bf16x8 a[4][2];
#pragma unroll
  for (int st = 0; st < 4; ++st) {
    const unsigned short* r = Ub + (size_t)(ws * 64 + st * 16 + c) * E_;
    a[st][0] = *(const bf16x8*)(r + g * 8);
    a[st][1] = *(const bf16x8*)(r + 32 + g * 8);
  }
  float pen[8];
#pragma unroll
  for (int j = 0; j < 8; ++j)
    pen[j] = (mb[(wn * 8 + j) * 16 + c] > 0.5f) ? 0.0f : -1e30f;

  float r[4][4];
#pragma unroll
  for (int st = 0; st < 4; ++st)
#pragma unroll
    for (int i = 0; i < 4; ++i) r[st][i] = -INFINITY;

#pragma unroll
  for (int j = 0; j < 8; ++j) {
    const int it = wn * 8 + j;
    const unsigned short* vr = Vb + (size_t)(it * 16 + c) * E_;
    bf16x8 b0 = *(const bf16x8*)(vr + g * 8);
    bf16x8 b1 = *(const bf16x8*)(vr + 32 + g * 8);
    f32x4 ci = {pen[j], pen[j], pen[j], pen[j]};
#pragma unroll
    for (int st = 0; st < 4; ++st) {
      f32x4 acc = __builtin_amdgcn_mfma_f32_16x16x32_bf16(a[st][0], b0, ci, 0, 0, 0);
      acc = __builtin_amdgcn_mfma_f32_16x16x32_bf16(a[st][1], b1, acc, 0, 0, 0);
      r[st][0] = fmaxf(r[st][0], acc[0]);
      r[st][1] = fmaxf(r[st][1], acc[1]);
      r[st][2] = fmaxf(r[st][2], acc[2]);
      r[st][3] = fmaxf(r[st][3], acc[3]);
    }
  }

  // reduce over the 16 column-lanes (xor 1,2,4,8 stays within kg group)
#pragma unroll
  for (int st = 0; st < 4; ++st)
#pragma unroll
    for (int i = 0; i < 4; ++i) {
      float v = r[st][i];
      v = fmaxf(v, __shfl_xor(v, 1)); v = fmaxf(v, __shfl_xor(v, 2));
      v = fmaxf(v, __shfl_xor(v, 4)); v = fmaxf(v, __shfl_xor(v, 8));
      r[st][i] = v;
    }

  if (c == 0) {
#pragma unroll
    for (int st = 0; st < 4; ++st)
#pragma unroll
      for (int i = 0; i < 4; ++i)
        comb[wn][ws * 64 + st * 16 + g * 4 + i] = r[st][i];
  }

  __syncthreads();

  if (tid < 128) {
    float v = fmaxf(fmaxf(comb[0][tid], comb[1][tid]),
                    fmaxf(comb[2][tid], comb[3][tid]));
    float bias = pb[0];
    out[(size_t)b * S_ + sq * 128 + tid] =
        (v < -1e29f) ? 0.0f : 1.0f / (1.0f + expf(-(v + bias)));
  }
}

extern "C" void kernel_launch(void* const* d_in, const int* in_sizes, int n_in,
                              void* d_out, int out_size, void* d_ws, size_t ws_size,
                              hipStream_t stream) {
  const float* ue = (const float*)d_in[0];
  const float* ve = (const float*)d_in[1];
  const float* cw = (const float*)d_in[2];
  const float* mask = (const float*)d_in[3];
  const float* pw = (const float*)d_in[4];
  const float* pb = (const float*)d_in[5];
  float* out = (float*)d_out;

  unsigned short* ubf = (unsigned short*)d_ws;
  unsigned short* vbf = ubf + (size_t)B_ * S_ * E_;

  // k1: 2*B*S rows, 64 rows per 256-thread block
  hipLaunchKernelGGL(prep_kernel, dim3(2 * B_ * S_ / 64), dim3(256), 0, stream,
                     ue, ve, cw, pw, ubf, vbf);
  // k2: 512 blocks x 512 thr, 2 blocks/CU
  hipLaunchKernelGGL(main_kernel, dim3(4 * B_), dim3(512), 0, stream,
                     ubf, vbf, mask, pb, out);
}

// Round 7
// 18.392 us; speedup vs baseline: 1.6960x; 1.6960x over previous
//
#include <hip/hip_runtime.h>
#include <hip/hip_bf16.h>
#include <math.h>

#define B_ 128
#define S_ 512
#define E_ 64
#define PAD_ 72  // bf16/row in LDS; 36-dword stride => bank-clean b128 access

typedef short bf16x8 __attribute__((ext_vector_type(8)));
typedef float f32x4 __attribute__((ext_vector_type(4)));

__device__ __forceinline__ unsigned short f2b(float f) {
  __hip_bfloat16 h = __float2bfloat16(f);
  unsigned short u;
  __builtin_memcpy(&u, &h, 2);
  return u;
}

// Fused, 256 blocks x 1024 thr (16 waves), 1 block/CU. Block = (batch, shalf).
// Staggered-half V: each block HBM-reads only its own 256 V rows (V read once
// chip-wide); the other 256 rows are read after barrier#1, by which time the
// XCD-swizzled sibling has them in the shared L2. Phase-2 own-half MFMA scan
// (pure LDS) overlaps the other-half loads.
__global__ __launch_bounds__(1024) void fused_kernel(
    const float* __restrict__ ue, const float* __restrict__ ve,
    const float* __restrict__ cw, const float* __restrict__ mask,
    const float* __restrict__ pw, const float* __restrict__ pb,
    float* __restrict__ out) {
  __shared__ unsigned short vlds[S_ * PAD_];   // 73728 B
  __shared__ unsigned short ulds[256 * PAD_];  // 36864 B
  __shared__ float comb[4][256];               // 4096 B

  // bijective swizzle: sibling blocks (same b, shalf 0/1) share an XCD (bx%8)
  const int bx = blockIdx.x;
  const int b = (bx & 7) * 16 + (bx >> 4);
  const int shalf = (bx >> 3) & 1;

  const int tid = threadIdx.x;
  const int wv = tid >> 6;  // 16 waves
  const int lane = tid & 63;
  const int c = lane & 15;  // MFMA col class / row-within-16
  const int g = lane >> 4;  // 16-elem column chunk / k-group
  const int ws = wv >> 2;   // s-split (0..3): 64 s-rows
  const int wn = wv & 3;    // n-split (0..3): 4 n-tiles per half

  const float w0 = pw[0];
  const float* __restrict__ vb = ve + (size_t)b * S_ * E_;
  const float* __restrict__ cwb = cw + (size_t)b * S_;
  const float* __restrict__ ub = ue + ((size_t)b * S_ + shalf * 256) * E_;
  const float* __restrict__ mb = mask + (size_t)b * S_;

  const int vrow_own = shalf * 256 + wv * 16 + c;  // own-half V row
  const int vrow_oth = (1 - shalf) * 256 + wv * 16 + c;
  const int urow = wv * 16 + c;  // block-local U row (0..255)

  // ---- Stage own-half V + U loads (64 B/lane each) ----
  const float* pv = vb + (size_t)vrow_own * E_ + g * 16;
  const float* pu = ub + (size_t)urow * E_ + g * 16;
  f32x4 xv[4], xu[4];
#pragma unroll
  for (int i = 0; i < 4; ++i) xv[i] = ((const f32x4*)pv)[i];
#pragma unroll
  for (int i = 0; i < 4; ++i) xu[i] = ((const f32x4*)pu)[i];
  float cwv = cwb[vrow_own];
  // mask penalties: own tiles shalf*16 + wn*4 + j, other tiles mirrored
  float pen[8];
#pragma unroll
  for (int j = 0; j < 4; ++j) {
    pen[j] = (mb[(shalf * 16 + wn * 4 + j) * 16 + c] > 0.5f) ? 0.0f : -1e30f;
    pen[4 + j] =
        (mb[((1 - shalf) * 16 + wn * 4 + j) * 16 + c] > 0.5f) ? 0.0f : -1e30f;
  }

  // ---- Normalize own-half V -> LDS ----
  {
    float ss = 0.f;
#pragma unroll
    for (int i = 0; i < 4; ++i)
#pragma unroll
      for (int j = 0; j < 4; ++j) ss = fmaf(xv[i][j], xv[i][j], ss);
    ss += __shfl_xor(ss, 16);
    ss += __shfl_xor(ss, 32);
    float s = (w0 * cwv) / fmaxf(sqrtf(ss), 1e-7f);
    bf16x8 o0, o1;
#pragma unroll
    for (int j = 0; j < 4; ++j) {
      o0[j] = (short)f2b(xv[0][j] * s); o0[4 + j] = (short)f2b(xv[1][j] * s);
      o1[j] = (short)f2b(xv[2][j] * s); o1[4 + j] = (short)f2b(xv[3][j] * s);
    }
    unsigned short* dst = vlds + (size_t)vrow_own * PAD_ + g * 16;
    *(bf16x8*)dst = o0;
    *(bf16x8*)(dst + 8) = o1;
  }
  // ---- Normalize U -> LDS ----
  {
    float ss = 0.f;
#pragma unroll
    for (int i = 0; i < 4; ++i)
#pragma unroll
      for (int j = 0; j < 4; ++j) ss = fmaf(xu[i][j], xu[i][j], ss);
    ss += __shfl_xor(ss, 16);
    ss += __shfl_xor(ss, 32);
    float s = 1.0f / fmaxf(sqrtf(ss), 1e-7f);
    bf16x8 o0, o1;
#pragma unroll
    for (int j = 0; j < 4; ++j) {
      o0[j] = (short)f2b(xu[0][j] * s); o0[4 + j] = (short)f2b(xu[1][j] * s);
      o1[j] = (short)f2b(xu[2][j] * s); o1[4 + j] = (short)f2b(xu[3][j] * s);
    }
    unsigned short* dst = ulds + (size_t)urow * PAD_ + g * 16;
    *(bf16x8*)dst = o0;
    *(bf16x8*)(dst + 8) = o1;
  }

  __syncthreads();  // barrier #1: own V-half + U ready

  // ---- Issue other-half V loads NOW (fly under the own-half MFMA scan;
  //      issued after the barrier so the barrier's vmcnt(0) drain can't eat
  //      them). Sibling block should have these rows in our XCD's L2. ----
  const float* py = vb + (size_t)vrow_oth * E_ + g * 16;
  f32x4 yv[4];
#pragma unroll
  for (int i = 0; i < 4; ++i) yv[i] = ((const f32x4*)py)[i];
  float cwo = cwb[vrow_oth];

  // ---- A-fragments from ulds: rows ws*64 + st*16 + c ----
  const unsigned short* urp = ulds + (size_t)(ws * 64 + c) * PAD_ + g * 8;
  bf16x8 a[4][2];
#pragma unroll
  for (int st = 0; st < 4; ++st) {
    a[st][0] = *(const bf16x8*)(urp + st * 16 * PAD_);
    a[st][1] = *(const bf16x8*)(urp + st * 16 * PAD_ + 32);
  }

  float r[4][4];
#pragma unroll
  for (int st = 0; st < 4; ++st)
#pragma unroll
    for (int i = 0; i < 4; ++i) r[st][i] = -INFINITY;

  // ---- Phase-2a: scan OWN half (tiles shalf*16 + wn*4 + j) ----
#pragma unroll
  for (int j = 0; j < 4; ++j) {
    const int it = shalf * 16 + wn * 4 + j;
    const unsigned short* vr = vlds + (size_t)(it * 16 + c) * PAD_ + g * 8;
    bf16x8 b0 = *(const bf16x8*)(vr);
    bf16x8 b1 = *(const bf16x8*)(vr + 32);
    f32x4 ci = {pen[j], pen[j], pen[j], pen[j]};
#pragma unroll
    for (int st = 0; st < 4; ++st) {
      f32x4 acc = __builtin_amdgcn_mfma_f32_16x16x32_bf16(a[st][0], b0, ci, 0, 0, 0);
      acc = __builtin_amdgcn_mfma_f32_16x16x32_bf16(a[st][1], b1, acc, 0, 0, 0);
      r[st][0] = fmaxf(r[st][0], acc[0]);
      r[st][1] = fmaxf(r[st][1], acc[1]);
      r[st][2] = fmaxf(r[st][2], acc[2]);
      r[st][3] = fmaxf(r[st][3], acc[3]);
    }
  }

  // ---- Normalize other-half V -> LDS ----
  {
    float ss = 0.f;
#pragma unroll
    for (int i = 0; i < 4; ++i)
#pragma unroll
      for (int j = 0; j < 4; ++j) ss = fmaf(yv[i][j], yv[i][j], ss);
    ss += __shfl_xor(ss, 16);
    ss += __shfl_xor(ss, 32);
    float s = (w0 * cwo) / fmaxf(sqrtf(ss), 1e-7f);
    bf16x8 o0, o1;
#pragma unroll
    for (int j = 0; j < 4; ++j) {
      o0[j] = (short)f2b(yv[0][j] * s); o0[4 + j] = (short)f2b(yv[1][j] * s);
      o1[j] = (short)f2b(yv[2][j] * s); o1[4 + j] = (short)f2b(yv[3][j] * s);
    }
    unsigned short* dst = vlds + (size_t)vrow_oth * PAD_ + g * 16;
    *(bf16x8*)dst = o0;
    *(bf16x8*)(dst + 8) = o1;
  }

  __syncthreads();  // barrier #2: other V-half ready

  // ---- Phase-2b: scan OTHER half ----
#pragma unroll
  for (int j = 0; j < 4; ++j) {
    const int it = (1 - shalf) * 16 + wn * 4 + j;
    const unsigned short* vr = vlds + (size_t)(it * 16 + c) * PAD_ + g * 8;
    bf16x8 b0 = *(const bf16x8*)(vr);
    bf16x8 b1 = *(const bf16x8*)(vr + 32);
    f32x4 ci = {pen[4 + j], pen[4 + j], pen[4 + j], pen[4 + j]};
#pragma unroll
    for (int st = 0; st < 4; ++st) {
      f32x4 acc = __builtin_amdgcn_mfma_f32_16x16x32_bf16(a[st][0], b0, ci, 0, 0, 0);
      acc = __builtin_amdgcn_mfma_f32_16x16x32_bf16(a[st][1], b1, acc, 0, 0, 0);
      r[st][0] = fmaxf(r[st][0], acc[0]);
      r[st][1] = fmaxf(r[st][1], acc[1]);
      r[st][2] = fmaxf(r[st][2], acc[2]);
      r[st][3] = fmaxf(r[st][3], acc[3]);
    }
  }

  // ---- Reduce over 16 column-lanes (xor 1,2,4,8 stays in kg group) ----
#pragma unroll
  for (int st = 0; st < 4; ++st)
#pragma unroll
    for (int i = 0; i < 4; ++i) {
      float v = r[st][i];
      v = fmaxf(v, __shfl_xor(v, 1)); v = fmaxf(v, __shfl_xor(v, 2));
      v = fmaxf(v, __shfl_xor(v, 4)); v = fmaxf(v, __shfl_xor(v, 8));
      r[st][i] = v;
    }

  if (c == 0) {
#pragma unroll
    for (int st = 0; st < 4; ++st)
#pragma unroll
      for (int i = 0; i < 4; ++i)
        comb[wn][ws * 64 + st * 16 + g * 4 + i] = r[st][i];
  }

  __syncthreads();  // barrier #3

  if (tid < 256) {
    float v = fmaxf(fmaxf(comb[0][tid], comb[1][tid]),
                    fmaxf(comb[2][tid], comb[3][tid]));
    float bias = pb[0];
    out[(size_t)b * S_ + shalf * 256 + tid] =
        (v < -1e29f) ? 0.0f : 1.0f / (1.0f + expf(-(v + bias)));
  }
}

extern "C" void kernel_launch(void* const* d_in, const int* in_sizes, int n_in,
                              void* d_out, int out_size, void* d_ws, size_t ws_size,
                              hipStream_t stream) {
  const float* ue = (const float*)d_in[0];
  const float* ve = (const float*)d_in[1];
  const float* cw = (const float*)d_in[2];
  const float* mask = (const float*)d_in[3];
  const float* pw = (const float*)d_in[4];
  const float* pb = (const float*)d_in[5];
  float* out = (float*)d_out;

  hipLaunchKernelGGL(fused_kernel, dim3(2 * B_), dim3(1024), 0, stream,
                     ue, ve, cw, mask, pw, pb, out);
}